// Round 1
// baseline (152.817 us; speedup 1.0000x reference)
//
#include <hip/hip_runtime.h>
#include <stdint.h>

#define NFREQ 256
#define NB 16
#define NT 4096
#define LOUT 1048832          // (4096+1)*256
#define TROWS 33              // t = j0-1 .. j0+31
#define TROW 132              // u32 per T row: 128 payload + 4 pad (528 B, 16B-aligned)

typedef __bf16 bf16;
typedef __bf16 bf16x8 __attribute__((ext_vector_type(8)));
typedef float floatx4 __attribute__((ext_vector_type(4)));

__device__ inline uint32_t f_as_u(float x) { union { float f; uint32_t u; } v; v.f = x; return v.u; }
__device__ inline uint32_t bf16r(float x) {     // RNE bf16 bits in low 16
    uint32_t u = f_as_u(x);
    return (u + 0x7fffu + ((u >> 16) & 1u)) >> 16;
}

// kbF frag-major: kbF[k'/32][n][k'%32] = Kb[n][k'],
//   Kb[n][f'] = (f'<256 ? K[n+256][f'] : K[n][f'-256]) / 128  (bf16 RNE)
// One wave's B-frag load (16 n-rows x 32 k) is then 1KB fully contiguous.
__global__ __launch_bounds__(256) void build_kb(const float* __restrict__ ker,
                                                bf16* __restrict__ kbF) {
    int idx = blockIdx.x * 256 + threadIdx.x;   // 131072 total
    int n = idx >> 9, f = idx & 511;
    float v = (f < 256) ? ker[(n + 256) * 256 + f] : ker[n * 256 + (f - 256)];
    uint32_t rr = bf16r(v * 0.0078125f);
    union { uint16_t u; bf16 b; } o; o.u = (uint16_t)rr;
    kbF[((size_t)(f >> 5) * 256 + n) * 32 + (f & 31)] = o.b;
}

// out[b][j*256+n] = sum_{f'<512} Avirt[j][f'] * Kb[n][f'],
//   Avirt[j][f'] = spec[b][f'&255][j-1+(f'>=256)]   (0 outside t-range)
// Block: 32 j x 256 n (finer tiles -> 2064 blocks, ~8/CU, 6 resident).
// LDS holds only T[33][256] bf16 (staged once, ONE barrier).
// B-frags stream global->VGPR from frag-major kbF (L2-hot, no barriers).
__global__ __launch_bounds__(256, 6) void imdct_gemm(const float* __restrict__ spec,
                                                     const bf16* __restrict__ kbF,
                                                     float* __restrict__ out) {
    __shared__ uint32_t Tt[TROWS * TROW];    // 17424 B -> LDS not binding (6 blk/CU via VGPR)

    const int jt = blockIdx.x;               // 0..128
    const int b  = blockIdx.y;
    const int tid = threadIdx.x, lane = tid & 63, w = tid >> 6;
    const int j0 = jt * 32;
    const float* sb = spec + (size_t)b * NFREQ * NT;

    // ---- stage T: T[t_local][f] bf16, t = j0-1+t_local, rows 0..32 ----
    {
        const int lpar = lane & 1, lt = lane >> 1;   // lt = t row 0..31
        const int fpw = w * 32;                      // wave's f-pair base
        const int t = j0 - 1 + lt;
        const bool tok = ((unsigned)t < (unsigned)NT);
        #pragma unroll
        for (int rb = 0; rb < 2; ++rb) {
            float v[16];
            #pragma unroll
            for (int i = 0; i < 16; ++i) {   // independent loads, 128B segments
                int fpi = rb * 16 + i;
                int f = (fpw + fpi) * 2 + lpar;
                v[i] = tok ? sb[(size_t)f * NT + t] : 0.0f;
            }
            // pack 4 f-pairs -> one b128 LDS write (conflict-free: 8 active
            // lanes/quarter cover all 32 banks exactly once)
            #pragma unroll
            for (int i = 0; i < 16; i += 4) {
                uint32_t pk[4];
                #pragma unroll
                for (int u = 0; u < 4; ++u) {
                    uint32_t h = bf16r(v[i + u]);
                    uint32_t o = (uint32_t)__shfl_xor((int)h, 1);
                    pk[u] = (h & 0xffffu) | (o << 16);
                }
                if (lpar == 0) {
                    uint4 q4; q4.x = pk[0]; q4.y = pk[1]; q4.z = pk[2]; q4.w = pk[3];
                    *reinterpret_cast<uint4*>(&Tt[lt * TROW + fpw + rb * 16 + i]) = q4;
                }
            }
        }
        // row 32 (t = j0+31)
        {
            int f = w * 64 + lane;
            int te = j0 + 31;
            float v = ((unsigned)te < (unsigned)NT) ? sb[(size_t)f * NT + te] : 0.0f;
            uint32_t h = bf16r(v); uint32_t o = (uint32_t)__shfl_xor((int)h, 1);
            if (lpar == 0) Tt[32 * TROW + w * 32 + lt] = (h & 0xffffu) | (o << 16);
        }
    }
    __syncthreads();                         // the ONLY barrier

    const int row16 = lane & 15, q = lane >> 4;
    floatx4 acc[2][4] = {};
    const uint8_t* Tb = reinterpret_cast<const uint8_t*>(Tt);
    const bf16* kbw = kbF + (size_t)w * 64 * 32;   // wave's n-slice base

    for (int kki = 0; kki < 8; ++kki) {
        const int toff = (kki >= 4) ? 1 : 0;
        const int kbyte = (kki & 3) * 128;
        #pragma unroll
        for (int ks = 0; ks < 2; ++ks) {
            const int kchunk = kki * 2 + ks;
            bf16x8 af[2], bfr[4];
            #pragma unroll
            for (int i = 0; i < 2; ++i)
                af[i] = *reinterpret_cast<const bf16x8*>(
                    Tb + (size_t)(i * 16 + row16 + toff) * (TROW * 4) + kbyte + ks * 64 + q * 16);
            #pragma unroll
            for (int jn = 0; jn < 4; ++jn)
                bfr[jn] = *reinterpret_cast<const bf16x8*>(
                    kbw + (size_t)kchunk * 8192 + (jn * 16 + row16) * 32 + q * 8);
            #pragma unroll
            for (int i = 0; i < 2; ++i)
                #pragma unroll
                for (int jn = 0; jn < 4; ++jn)
                    acc[i][jn] = __builtin_amdgcn_mfma_f32_16x16x32_bf16(af[i], bfr[jn], acc[i][jn], 0, 0, 0);
        }
    }

    // epilogue: C/D layout col=lane&15 (n), row=q*4+e (j within 16)
    #pragma unroll
    for (int i = 0; i < 2; ++i) {
        #pragma unroll
        for (int e = 0; e < 4; ++e) {
            int j = j0 + i * 16 + q * 4 + e;
            if (j <= 4096) {
                float* orow = out + (size_t)b * LOUT + (size_t)j * 256 + w * 64;
                #pragma unroll
                for (int jn = 0; jn < 4; ++jn)
                    orow[jn * 16 + row16] = acc[i][jn][e];
            }
        }
    }
}

extern "C" void kernel_launch(void* const* d_in, const int* in_sizes, int n_in,
                              void* d_out, int out_size, void* d_ws, size_t ws_size,
                              hipStream_t stream) {
    const float* spec = (const float*)d_in[0];   // [16][1][256][4096] fp32
    const float* ker  = (const float*)d_in[1];   // [512][256] fp32
    float* out = (float*)d_out;                  // [16][1048832] fp32

    bf16* kbF = (bf16*)d_ws;                     // 256 KB scratch

    build_kb<<<512, 256, 0, stream>>>(ker, kbF);
    imdct_gemm<<<dim3(129, NB), 256, 0, stream>>>(spec, kbF, out);
}

// Round 2
// 145.093 us; speedup vs baseline: 1.0532x; 1.0532x over previous
//
#include <hip/hip_runtime.h>
#include <stdint.h>

#define NFREQ 256
#define NB 16
#define NT 4096
#define LOUT 1048832          // (4096+1)*256
#define TROWS 129             // t = j0-1 .. j0+127
#define TROW 132              // u32 per T row: 128 payload + 4 pad (528 B, 16B-aligned)

typedef __bf16 bf16;
typedef __bf16 bf16x8 __attribute__((ext_vector_type(8)));
typedef float floatx4 __attribute__((ext_vector_type(4)));

__device__ inline uint32_t f_as_u(float x) { union { float f; uint32_t u; } v; v.f = x; return v.u; }
__device__ inline uint32_t bf16r(float x) {     // RNE bf16 bits in low 16
    uint32_t u = f_as_u(x);
    return (u + 0x7fffu + ((u >> 16) & 1u)) >> 16;
}

// kbF frag-major: kbF[k'/32][n][k'%32] = Kb[n][k'],
//   Kb[n][f'] = (f'<256 ? K[n+256][f'] : K[n][f'-256]) / 128  (bf16 RNE)
__global__ __launch_bounds__(256) void build_kb(const float* __restrict__ ker,
                                                bf16* __restrict__ kbF) {
    int idx = blockIdx.x * 256 + threadIdx.x;   // 131072 total
    int n = idx >> 9, f = idx & 511;
    float v = (f < 256) ? ker[(n + 256) * 256 + f] : ker[n * 256 + (f - 256)];
    uint32_t rr = bf16r(v * 0.0078125f);
    union { uint16_t u; bf16 b; } o; o.u = (uint16_t)rr;
    kbF[((size_t)(f >> 5) * 256 + n) * 32 + (f & 31)] = o.b;
}

// out[b][j*256+n] = sum_{f'<512} Avirt[j][f'] * Kb[n][f'],
//   Avirt[j][f'] = spec[b][f'&255][j-1+(f'>=256)]   (0 outside t-range)
// Block: 128 j x 256 n (4 waves, each 128j x 64n). B-traffic per output halved
// vs j=64. LDS = T[129][256] bf16 (68 KB -> 2 blocks/CU). B-frags stream
// global->VGPR with explicit 1-chunk register ping-pong prefetch (bP/bQ) so
// the L2 latency rides under the 32-MFMA cluster (counted vmcnt, no drain).
__global__ __launch_bounds__(256, 2) void imdct_gemm(const float* __restrict__ spec,
                                                     const bf16* __restrict__ kbF,
                                                     float* __restrict__ out) {
    __shared__ uint32_t Tt[TROWS * TROW];    // 68112 B

    const int jt = blockIdx.x;               // 0..32
    const int b  = blockIdx.y;
    const int tid = threadIdx.x, lane = tid & 63, w = tid >> 6;
    const int j0 = jt * 128;
    const float* sb = spec + (size_t)b * NFREQ * NT;

    // ---- stage T: T[tl][f] bf16, t = j0-1+tl, rows 0..128 ----
    {
        const int lpar = lane & 1, lt = lane >> 1;   // lt = t within 32-row chunk
        const int fpw = w * 32;                      // wave's f-pair base
        #pragma unroll
        for (int rb = 0; rb < 8; ++rb) {
            float v[16];
            #pragma unroll
            for (int i = 0; i < 16; ++i) {   // independent loads, 128B segments
                int r = rb * 16 + i;
                int tc = r >> 5, fpi = r & 31;
                int f = (fpw + fpi) * 2 + lpar;
                int t = j0 - 1 + tc * 32 + lt;
                v[i] = ((unsigned)t < (unsigned)NT) ? sb[(size_t)f * NT + t] : 0.0f;
            }
            #pragma unroll
            for (int i = 0; i < 16; i += 4) {
                int r = rb * 16 + i;
                int tc = r >> 5, fpi = r & 31;
                int tl = tc * 32 + lt;
                uint32_t pk[4];
                #pragma unroll
                for (int u = 0; u < 4; ++u) {
                    uint32_t h = bf16r(v[i + u]);
                    uint32_t o = (uint32_t)__shfl_xor((int)h, 1);
                    pk[u] = (h & 0xffffu) | (o << 16);
                }
                if (lpar == 0) {
                    uint4 q4; q4.x = pk[0]; q4.y = pk[1]; q4.z = pk[2]; q4.w = pk[3];
                    *reinterpret_cast<uint4*>(&Tt[tl * TROW + fpw + fpi]) = q4;
                }
            }
        }
        // row 128 (t = j0+127)
        {
            int f = w * 64 + lane;
            int te = j0 + 127;
            float v = ((unsigned)te < (unsigned)NT) ? sb[(size_t)f * NT + te] : 0.0f;
            uint32_t h = bf16r(v); uint32_t o = (uint32_t)__shfl_xor((int)h, 1);
            if (lpar == 0) Tt[128 * TROW + w * 32 + lt] = (h & 0xffffu) | (o << 16);
        }
    }
    __syncthreads();                         // the ONLY barrier

    const int row16 = lane & 15, q = lane >> 4;
    floatx4 acc[8][4] = {};
    const uint8_t* Tb = reinterpret_cast<const uint8_t*>(Tt);
    const bf16* kbw = kbF + (size_t)w * 64 * 32;   // wave's n-slice base

    // chunk c in [0,16): A row-offset toff = c>>3, A byte col = (c&7)*64,
    // B frag block = kbw + c*8192.
#define LOADB(dst, c) { \
    _Pragma("unroll") \
    for (int jn = 0; jn < 4; ++jn) \
        dst[jn] = *reinterpret_cast<const bf16x8*>( \
            kbw + (size_t)(c) * 8192 + (jn * 16 + row16) * 32 + q * 8); }

#define LOADA(dst, c) { \
    _Pragma("unroll") \
    for (int i = 0; i < 8; ++i) \
        dst[i] = *reinterpret_cast<const bf16x8*>( \
            Tb + (size_t)(i * 16 + row16 + ((c) >> 3)) * 528 + ((c) & 7) * 64 + q * 16); }

#define DOMFMA(afr, bfr) { \
    _Pragma("unroll") \
    for (int i = 0; i < 8; ++i) \
        _Pragma("unroll") \
        for (int jn = 0; jn < 4; ++jn) \
            acc[i][jn] = __builtin_amdgcn_mfma_f32_16x16x32_bf16(afr[i], bfr[jn], acc[i][jn], 0, 0, 0); }

    bf16x8 bP[4], bQ[4], af[8];
    LOADB(bP, 0);
    #pragma unroll
    for (int cc = 0; cc < 8; ++cc) {
        LOADB(bQ, cc * 2 + 1);              // prefetch odd chunk
        LOADA(af, cc * 2);
        DOMFMA(af, bP);                     // compute even chunk (bP in regs)
        if (cc < 7) LOADB(bP, cc * 2 + 2);  // prefetch next even chunk
        LOADA(af, cc * 2 + 1);
        DOMFMA(af, bQ);                     // compute odd chunk
    }
#undef LOADB
#undef LOADA
#undef DOMFMA

    // epilogue: C/D layout col=lane&15 (n), row=q*4+e (j within 16)
    #pragma unroll
    for (int i = 0; i < 8; ++i) {
        #pragma unroll
        for (int e = 0; e < 4; ++e) {
            int j = j0 + i * 16 + q * 4 + e;
            if (j <= 4096) {
                float* orow = out + (size_t)b * LOUT + (size_t)j * 256 + w * 64;
                #pragma unroll
                for (int jn = 0; jn < 4; ++jn)
                    orow[jn * 16 + row16] = acc[i][jn][e];
            }
        }
    }
}

extern "C" void kernel_launch(void* const* d_in, const int* in_sizes, int n_in,
                              void* d_out, int out_size, void* d_ws, size_t ws_size,
                              hipStream_t stream) {
    const float* spec = (const float*)d_in[0];   // [16][1][256][4096] fp32
    const float* ker  = (const float*)d_in[1];   // [512][256] fp32
    float* out = (float*)d_out;                  // [16][1048832] fp32

    bf16* kbF = (bf16*)d_ws;                     // 256 KB scratch

    build_kb<<<512, 256, 0, stream>>>(ker, kbF);
    imdct_gemm<<<dim3(33, NB), 256, 0, stream>>>(spec, kbF, out);
}